// Round 4
// baseline (4910.582 us; speedup 1.0000x reference)
//
#include <hip/hip_runtime.h>
#include <math.h>

// Problem constants
#define B_    4
#define R_    8
#define H_    256
#define W_    256
#define HW    65536
#define NPIX  (B_*HW)      // 262144
#define CIN1  16
#define CMID  32
#define COUT2 32
#define EPS_  1e-5

// ---------------- workspace layout (bytes) ----------------
#define OFF_OFFSETS  256         // int[33]
#define OFF_SCALE1   768         // float[32]
#define OFF_SHIFT1   896         // float[32]
#define OFF_SCALE2   1024        // float[32]
#define OFF_SHIFT2   1152        // float[32]
#define OFF_STATP    8192        // double[128*32*2] = 65536 B  (overlays rowcnt in setup phase)
#define OFF_ROWCNT   8192        // int[4*256*8] = 32768 B  (dead after scan2, before stats)
#define OFF_ROWBASE  73728       // int[4*256*8] = 32768 B  (LIVE until conv2 - dedicated)
#define OFF_POOLED1  106496      // float[4*16*9]
#define OFF_POOLED2  110592      // float[4*32*9]
#define OFF_KBUF1    139264     // float[147456]   = 589824 B
#define OFF_KBUF2    729088     // float[294912]   = 1179648 B
#define OFF_RMAP     1908736    // int[262144] = 1 MB; dead after scatter -> reused as rowsum
#define OFF_LISTS    2957312    // int[262144]     = 1048576 B
#define OFF_XT       4005888    // float[4*65536*16] = 16777216 B
#define OFF_RAWY1    20783104   // float[4*65536*32] = 33554432 B
// total ~54.3 MB

// ---------------- small setup kernels ----------------

// NCHW (4,16,256,256) -> NHWC (4,65536,16)
__global__ __launch_bounds__(256)
void transpose16_kernel(const float* __restrict__ X, float* __restrict__ Xt) {
    __shared__ float t[16][257];
    const int b   = blockIdx.y;
    const int px0 = blockIdx.x * 256;
    #pragma unroll
    for (int c = 0; c < 16; ++c)
        t[c][threadIdx.x] = X[((size_t)b*16 + c)*HW + px0 + threadIdx.x];
    __syncthreads();
    float4* dst = (float4*)(Xt + ((size_t)b*HW + px0 + threadIdx.x)*16);
    #pragma unroll
    for (int c4 = 0; c4 < 4; ++c4) {
        float4 v;
        v.x = t[c4*4+0][threadIdx.x];
        v.y = t[c4*4+1][threadIdx.x];
        v.z = t[c4*4+2][threadIdx.x];
        v.w = t[c4*4+3][threadIdx.x];
        dst[c4] = v;
    }
}

// One block per image row: argmax over 8 histmap channels -> rmap, per-(b,row,g) counts
__global__ __launch_bounds__(256)
void regionmap_kernel(const float* __restrict__ hm, int* __restrict__ rmap,
                      int* __restrict__ rowcnt) {
    __shared__ int lcnt[8];
    if (threadIdx.x < 8) lcnt[threadIdx.x] = 0;
    __syncthreads();
    const int r = blockIdx.x;
    const int b = blockIdx.y;
    const int pix = r*256 + threadIdx.x;
    const float* hp = hm + (size_t)b*8*HW + pix;
    float best = hp[0]; int g = 0;
    #pragma unroll
    for (int gg = 1; gg < 8; ++gg) {
        float v = hp[(size_t)gg*HW];
        if (v > best) { best = v; g = gg; }
    }
    rmap[(size_t)b*HW + pix] = g;
    atomicAdd(&lcnt[g], 1);
    __syncthreads();
    if (threadIdx.x < 8) rowcnt[((b*H_ + r)<<3) + threadIdx.x] = lcnt[threadIdx.x];
}

// Hierarchical scan: rowcnt -> offs[33] (bucket starts) and rowbase (row segment starts)
__global__ __launch_bounds__(256)
void scan2_kernel(const int* __restrict__ rowcnt, int* __restrict__ offs,
                  int* __restrict__ rowbase) {
    const int tid   = threadIdx.x;
    const int pair  = tid >> 3;   // 0..31 = b*8+g
    const int chunk = tid & 7;    // rows [chunk*32, chunk*32+32)
    const int b = pair >> 3, g = pair & 7;
    __shared__ int ctot[32][8];
    __shared__ int cbase[32][8];
    __shared__ int pstart[33];
    int run = 0;
    #pragma unroll 4
    for (int rr = 0; rr < 32; ++rr) {
        const int r = chunk*32 + rr;
        run += rowcnt[((b*H_ + r)<<3) + g];
    }
    ctot[pair][chunk] = run;
    __syncthreads();
    if (tid < 32) {
        int acc = 0;
        #pragma unroll
        for (int ch = 0; ch < 8; ++ch) { cbase[tid][ch] = acc; acc += ctot[tid][ch]; }
        ctot[tid][0] = acc;  // pair total
    }
    __syncthreads();
    if (tid == 0) {
        int acc = 0;
        for (int pp = 0; pp < 32; ++pp) { pstart[pp] = acc; offs[pp] = acc; acc += ctot[pp][0]; }
        pstart[32] = acc; offs[32] = acc;
    }
    __syncthreads();
    int base = pstart[pair] + cbase[pair][chunk];
    for (int rr = 0; rr < 32; ++rr) {
        const int r = chunk*32 + rr;
        const int idx = ((b*H_ + r)<<3) + g;
        rowbase[idx] = base;
        base += rowcnt[idx];
    }
}

// Row-ordered scatter: lists sorted by row within each (b,g) bucket.
__global__ __launch_bounds__(256)
void scatter_kernel(const int* __restrict__ rmap, const int* __restrict__ rowbase,
                    int* __restrict__ lists) {
    __shared__ int lpos[8];
    const int r = blockIdx.x;
    const int b = blockIdx.y;
    if (threadIdx.x < 8) lpos[threadIdx.x] = rowbase[((b*H_ + r)<<3) + threadIdx.x];
    __syncthreads();
    const int pix = r*256 + threadIdx.x;
    const int g = rmap[(size_t)b*HW + pix];
    const int slot = atomicAdd(&lpos[g], 1);
    lists[slot] = pix;
}

// ---------------- adaptive avg pool, two-stage parallel ----------------
template<int C, bool FUSE>
__global__ __launch_bounds__(256)
void rowsum_kernel(const float* __restrict__ Yin, const float* __restrict__ scale,
                   const float* __restrict__ shift, float* __restrict__ rowsum) {
    constexpr int NS = 256 / C;
    const int h = blockIdx.x;
    const int b = blockIdx.y;
    const int c = threadIdx.x & (C-1);
    float sc = 0.f, sh = 0.f;
    if (FUSE) { sc = scale[c]; sh = shift[c]; }
    const float* row = Yin + ((size_t)b*HW + (size_t)h*W_)*C;
    const int s = threadIdx.x / C;
    float s0 = 0.f, s1 = 0.f, s2 = 0.f;
    for (int w = s; w < W_; w += NS) {
        float v = row[(size_t)w*C + c];
        if (FUSE) v = fmaxf(fmaf(v, sc, sh), 0.f);
        if (w < 86)             s0 += v;
        if (w >= 85 && w < 171) s1 += v;
        if (w >= 170)           s2 += v;
    }
    __shared__ float red[256];
    float* outp = rowsum + (((size_t)b*H_ + h)*3)*C;
    float ss[3] = {s0, s1, s2};
    #pragma unroll
    for (int j = 0; j < 3; ++j) {
        red[threadIdx.x] = ss[j];
        __syncthreads();
        for (int st = 128; st >= C; st >>= 1) {
            if (threadIdx.x < st) red[threadIdx.x] += red[threadIdx.x + st];
            __syncthreads();
        }
        if (threadIdx.x < C) outp[j*C + threadIdx.x] = red[threadIdx.x];
        __syncthreads();
    }
}

template<int C>
__global__ __launch_bounds__(256)
void binreduce_kernel(const float* __restrict__ rowsum, float* __restrict__ pooled) {
    constexpr int NS = 256 / C;
    const int bin = blockIdx.x;          // 0..8
    const int b   = blockIdx.y;
    const int bi = bin/3, bj = bin%3;
    const int h0 = (bi*H_)/3,  h1 = ((bi+1)*H_ + 2)/3;
    const int w0 = (bj*W_)/3,  w1 = ((bj+1)*W_ + 2)/3;
    const int npx = (h1-h0)*(w1-w0);
    const int c = threadIdx.x & (C-1);
    const int s = threadIdx.x / C;
    float sum = 0.f;
    for (int h = h0 + s; h < h1; h += NS)
        sum += rowsum[(((size_t)b*H_ + h)*3 + bj)*C + c];
    __shared__ float red[256];
    red[threadIdx.x] = sum;
    __syncthreads();
    for (int st = 128; st >= C; st >>= 1) {
        if (threadIdx.x < st) red[threadIdx.x] += red[threadIdx.x + st];
        __syncthreads();
    }
    if (threadIdx.x < C)
        pooled[((size_t)b*C + threadIdx.x)*9 + bin] = red[threadIdx.x] / (float)npx;
}

// ---------------- per-sample kernel generation ----------------
template<int CIN>
__global__ __launch_bounds__(256)
void kgen_kernel(const float* __restrict__ pooled,
                 const float* __restrict__ w1, const float* __restrict__ b1,
                 const float* __restrict__ w2, const float* __restrict__ b2,
                 float* __restrict__ kbuf) {
    __shared__ float t[8][9];
    const int bg = blockIdx.x;
    const int b = bg >> 3, g = bg & 7;
    if (threadIdx.x < 72) {
        const int r = threadIdx.x / 9, ij = threadIdx.x % 9;
        float s = b1[g*8 + r];
        const float* wrow = w1 + (g*8 + r)*CIN;
        const float* prow = pooled + (size_t)b*CIN*9 + ij;
        #pragma unroll
        for (int c = 0; c < CIN; ++c) s += wrow[c] * prow[c*9];
        t[r][ij] = 1.f / (1.f + expf(-s));
    }
    __syncthreads();
    constexpr int TOT = CIN*9*32;
    for (int e = threadIdx.x; e < TOT; e += 256) {
        const int o    = e & 31;
        const int rest = e >> 5;
        const int ij   = rest % 9;
        const int c    = rest / 9;
        const int oc   = o*CIN + c;
        const float* w2row = w2 + ((size_t)g*(CIN*32) + oc)*8;
        float s = b2[(size_t)g*(CIN*32) + oc];
        #pragma unroll
        for (int r = 0; r < 8; ++r) s += w2row[r] * t[r][ij];
        kbuf[(size_t)bg*TOT + e] = s;
    }
}

// ---------------- main dynamic-region conv (slice-resident, wave-per-region) ----------------
// Block = (og, slice of 4 rows). 512 threads = 8 waves; wave w processes region g=w
// using the row-sorted global lists (segment bounds from rowbase). Weights for all
// 8 regions x 16 outs x 16-channel phase live in LDS (36 KB); weight reads are
// wave-uniform (broadcast). CIN=32 runs as 2 channel-phases, acc persists in regs.
template<int CIN, int PHASES, bool FUSE, bool NHWC_OUT>
__global__ __launch_bounds__(512, 4)
void conv_kernel(const float* __restrict__ Xin, const float* __restrict__ kbuf,
                 const int* __restrict__ lists, const int* __restrict__ rowbase,
                 const int* __restrict__ offs,
                 const float* __restrict__ scale, const float* __restrict__ shift,
                 float* __restrict__ Yout) {
    constexpr int PC = CIN / PHASES;           // channels per phase = 16
    __shared__ float wl[8 * PC*9 * 16];        // [g][cc*9+ij][o] = 36 KB
    __shared__ float sc[CIN], sh[CIN];
    __shared__ int scnt[8], sbase[8];

    const int og  = blockIdx.x;                // 0..1 (16 outputs each)
    const int s   = blockIdx.y;                // 0..255
    const int b   = s >> 6;
    const int r0  = (s & 63) * 4;
    const int tid = threadIdx.x;
    const int wave = tid >> 6, lane = tid & 63;

    if (tid < 8) {
        const int g  = tid;
        const int st = rowbase[((b*H_ + r0)<<3) + g];
        const int en = (r0 + 4 < H_) ? rowbase[((b*H_ + r0 + 4)<<3) + g]
                                     : offs[b*8 + g + 1];
        sbase[g] = st; scnt[g] = en - st;
    }
    if (FUSE && tid < CIN) { sc[tid] = scale[tid]; sh[tid] = shift[tid]; }
    __syncthreads();

    int maxc = 0;
    #pragma unroll
    for (int g = 0; g < 8; ++g) maxc = max(maxc, scnt[g]);
    const int iters = (maxc + 127) >> 7;

    const int g    = wave;
    const int cnt  = scnt[g];
    const int base = sbase[g];
    const float* __restrict__ Xb = Xin + (size_t)b * HW * CIN;
    const size_t kb_bg = (size_t)b*8 * (CIN*9*32);

    for (int it = 0; it < iters; ++it) {
        const int ep   = (it << 7) + lane;
        const bool val0 = ep < cnt;
        const bool val1 = ep + 64 < cnt;
        int px0 = 0, px1 = 0;
        if (val0) px0 = lists[base + ep];
        if (val1) px1 = lists[base + ep + 64];
        const int h0 = px0 >> 8, w0 = px0 & 255;
        const int h1 = px1 >> 8, w1 = px1 & 255;

        float acc0[16], acc1[16];
        #pragma unroll
        for (int o = 0; o < 16; ++o) { acc0[o] = 0.f; acc1[o] = 0.f; }

        #pragma unroll 1
        for (int ph = 0; ph < PHASES; ++ph) {
            if (PHASES > 1 || it == 0) {
                __syncthreads();   // prior readers done before overwrite
                for (int e = tid; e < 8*PC*9*16; e += 512) {
                    const int o  = e & 15;
                    int rest = e >> 4;
                    const int ij = rest % 9; rest /= 9;
                    const int cc = rest & (PC - 1);
                    const int gg = rest >> 4;
                    wl[e] = kbuf[kb_bg + (size_t)gg*(CIN*9*32)
                                 + ((size_t)(ph*PC + cc)*9 + ij)*32 + og*16 + o];
                }
                __syncthreads();
            }

            #pragma unroll 1
            for (int di = -1; di <= 1; ++di) {
                #pragma unroll 1
                for (int dj = -1; dj <= 1; ++dj) {
                    const int ij = (di+1)*3 + (dj+1);
                    const bool v0 = val0 && ((unsigned)(h0+di) < (unsigned)H_) && ((unsigned)(w0+dj) < (unsigned)W_);
                    const bool v1 = val1 && ((unsigned)(h1+di) < (unsigned)H_) && ((unsigned)(w1+dj) < (unsigned)W_);
                    const float* r0p = Xb + (long)(px0 + di*W_ + dj)*CIN + ph*PC;
                    const float* r1p = Xb + (long)(px1 + di*W_ + dj)*CIN + ph*PC;
                    #pragma unroll
                    for (int c4 = 0; c4 < PC/4; ++c4) {
                        float4 x0 = make_float4(0.f,0.f,0.f,0.f);
                        float4 x1 = make_float4(0.f,0.f,0.f,0.f);
                        if (v0) {
                            x0 = *(const float4*)(r0p + (c4<<2));
                            if (FUSE) {
                                const int cb = ph*PC + (c4<<2);
                                x0.x = fmaxf(fmaf(x0.x, sc[cb+0], sh[cb+0]), 0.f);
                                x0.y = fmaxf(fmaf(x0.y, sc[cb+1], sh[cb+1]), 0.f);
                                x0.z = fmaxf(fmaf(x0.z, sc[cb+2], sh[cb+2]), 0.f);
                                x0.w = fmaxf(fmaf(x0.w, sc[cb+3], sh[cb+3]), 0.f);
                            }
                        }
                        if (v1) {
                            x1 = *(const float4*)(r1p + (c4<<2));
                            if (FUSE) {
                                const int cb = ph*PC + (c4<<2);
                                x1.x = fmaxf(fmaf(x1.x, sc[cb+0], sh[cb+0]), 0.f);
                                x1.y = fmaxf(fmaf(x1.y, sc[cb+1], sh[cb+1]), 0.f);
                                x1.z = fmaxf(fmaf(x1.z, sc[cb+2], sh[cb+2]), 0.f);
                                x1.w = fmaxf(fmaf(x1.w, sc[cb+3], sh[cb+3]), 0.f);
                            }
                        }
                        #pragma unroll
                        for (int k = 0; k < 4; ++k) {
                            const float xa = (k==0)?x0.x:((k==1)?x0.y:((k==2)?x0.z:x0.w));
                            const float xb = (k==0)?x1.x:((k==1)?x1.y:((k==2)?x1.z:x1.w));
                            // wave-uniform address -> LDS broadcast, conflict-free
                            const float4* wrow = (const float4*)&wl[(((g*PC) + (c4<<2) + k)*9 + ij)*16];
                            #pragma unroll
                            for (int o4 = 0; o4 < 4; ++o4) {
                                const float4 w4 = wrow[o4];
                                acc0[o4*4+0] = fmaf(xa, w4.x, acc0[o4*4+0]);
                                acc0[o4*4+1] = fmaf(xa, w4.y, acc0[o4*4+1]);
                                acc0[o4*4+2] = fmaf(xa, w4.z, acc0[o4*4+2]);
                                acc0[o4*4+3] = fmaf(xa, w4.w, acc0[o4*4+3]);
                                acc1[o4*4+0] = fmaf(xb, w4.x, acc1[o4*4+0]);
                                acc1[o4*4+1] = fmaf(xb, w4.y, acc1[o4*4+1]);
                                acc1[o4*4+2] = fmaf(xb, w4.z, acc1[o4*4+2]);
                                acc1[o4*4+3] = fmaf(xb, w4.w, acc1[o4*4+3]);
                            }
                        }
                    }
                }
            }
        }

        if (NHWC_OUT) {
            if (val0) {
                float4* d = (float4*)(Yout + ((size_t)b*HW + px0)*32 + og*16);
                #pragma unroll
                for (int o4 = 0; o4 < 4; ++o4)
                    d[o4] = make_float4(acc0[o4*4+0], acc0[o4*4+1], acc0[o4*4+2], acc0[o4*4+3]);
            }
            if (val1) {
                float4* d = (float4*)(Yout + ((size_t)b*HW + px1)*32 + og*16);
                #pragma unroll
                for (int o4 = 0; o4 < 4; ++o4)
                    d[o4] = make_float4(acc1[o4*4+0], acc1[o4*4+1], acc1[o4*4+2], acc1[o4*4+3]);
            }
        } else {
            if (val0) {
                float* d = Yout + ((size_t)b*32 + og*16)*HW + px0;
                #pragma unroll
                for (int o = 0; o < 16; ++o) d[(size_t)o*HW] = acc0[o];
            }
            if (val1) {
                float* d = Yout + ((size_t)b*32 + og*16)*HW + px1;
                #pragma unroll
                for (int o = 0; o < 16; ++o) d[(size_t)o*HW] = acc1[o];
            }
        }
    }
}

// ---------------- BN statistics ----------------
// NHWC (B,HW,32): 128 blocks x 2048 pixels
__global__ __launch_bounds__(256)
void stats_nhwc_kernel(const float* __restrict__ Y, double* __restrict__ statp) {
    const int c = threadIdx.x & 31;
    const int s = threadIdx.x >> 5;  // 0..7
    const int p0 = blockIdx.x * 2048;
    double sum = 0.0, sq = 0.0;
    for (int p = p0 + s; p < p0 + 2048; p += 8) {
        const float v = Y[(size_t)p*32 + c];
        sum += v; sq += (double)v*v;
    }
    __shared__ double rs[256], rq[256];
    rs[threadIdx.x] = sum; rq[threadIdx.x] = sq;
    __syncthreads();
    for (int st = 128; st >= 32; st >>= 1) {
        if (threadIdx.x < st) { rs[threadIdx.x] += rs[threadIdx.x+st]; rq[threadIdx.x] += rq[threadIdx.x+st]; }
        __syncthreads();
    }
    if (threadIdx.x < 32) {
        statp[((size_t)blockIdx.x*32 + threadIdx.x)*2 + 0] = rs[threadIdx.x];
        statp[((size_t)blockIdx.x*32 + threadIdx.x)*2 + 1] = rq[threadIdx.x];
    }
}

__global__ __launch_bounds__(256)
void stats_nchw_kernel(const float* __restrict__ Y, double* __restrict__ statp) {
    const int co = blockIdx.y, chunk = blockIdx.x;
    double sum = 0.0, sq = 0.0;
    for (int b = 0; b < B_; ++b) {
        const float* base = Y + ((size_t)b*32 + co)*HW + chunk*8192;
        for (int k = threadIdx.x; k < 8192; k += 256) {
            const float v = base[k];
            sum += v; sq += (double)v*v;
        }
    }
    __shared__ double rs[256], rq[256];
    rs[threadIdx.x] = sum; rq[threadIdx.x] = sq;
    __syncthreads();
    for (int st = 128; st >= 1; st >>= 1) {
        if (threadIdx.x < st) { rs[threadIdx.x] += rs[threadIdx.x+st]; rq[threadIdx.x] += rq[threadIdx.x+st]; }
        __syncthreads();
    }
    if (threadIdx.x == 0) {
        statp[((size_t)chunk*32 + co)*2 + 0] = rs[0];
        statp[((size_t)chunk*32 + co)*2 + 1] = rq[0];
    }
}

__global__ void bnfinal_kernel(const double* __restrict__ statp, int nblk,
                               const float* __restrict__ gamma, const float* __restrict__ beta,
                               float* __restrict__ scale, float* __restrict__ shift) {
    const int c = threadIdx.x;
    if (c < 32) {
        double s = 0.0, q = 0.0;
        for (int k = 0; k < nblk; ++k) {
            s += statp[((size_t)k*32 + c)*2 + 0];
            q += statp[((size_t)k*32 + c)*2 + 1];
        }
        const double N = (double)NPIX;
        const double mean = s / N;
        const double var  = q / N - mean*mean;
        const double inv  = 1.0 / sqrt(var + EPS_);
        scale[c] = (float)((double)gamma[c] * inv);
        shift[c] = (float)((double)beta[c] - mean * (double)gamma[c] * inv);
    }
}

__global__ __launch_bounds__(256)
void eltwise_kernel(float* __restrict__ Y, const float* __restrict__ scale,
                    const float* __restrict__ shift) {
    const int idx = blockIdx.x*256 + threadIdx.x;        // float4 index
    const int c = (idx >> 14) & 31;
    const float s = scale[c], sh = shift[c];
    float4 v = ((float4*)Y)[idx];
    v.x = fmaxf(fmaf(v.x, s, sh), 0.f);
    v.y = fmaxf(fmaf(v.y, s, sh), 0.f);
    v.z = fmaxf(fmaf(v.z, s, sh), 0.f);
    v.w = fmaxf(fmaf(v.w, s, sh), 0.f);
    ((float4*)Y)[idx] = v;
}

// ---------------- launcher ----------------
extern "C" void kernel_launch(void* const* d_in, const int* in_sizes, int n_in,
                              void* d_out, int out_size, void* d_ws, size_t ws_size,
                              hipStream_t stream) {
    const float* x    = (const float*)d_in[0];
    const float* hm   = (const float*)d_in[1];
    const float* w1_1 = (const float*)d_in[2];
    const float* b1_1 = (const float*)d_in[3];
    const float* w2_1 = (const float*)d_in[4];
    const float* b2_1 = (const float*)d_in[5];
    const float* g1   = (const float*)d_in[6];
    const float* be1  = (const float*)d_in[7];
    const float* w1_2 = (const float*)d_in[8];
    const float* b1_2 = (const float*)d_in[9];
    const float* w2_2 = (const float*)d_in[10];
    const float* b2_2 = (const float*)d_in[11];
    const float* g2   = (const float*)d_in[12];
    const float* be2  = (const float*)d_in[13];
    float* out = (float*)d_out;

    char* ws = (char*)d_ws;
    int*    offs    = (int*)(ws + OFF_OFFSETS);
    float*  scale1  = (float*)(ws + OFF_SCALE1);
    float*  shift1  = (float*)(ws + OFF_SHIFT1);
    float*  scale2  = (float*)(ws + OFF_SCALE2);
    float*  shift2  = (float*)(ws + OFF_SHIFT2);
    double* statp   = (double*)(ws + OFF_STATP);
    int*    rowcnt  = (int*)(ws + OFF_ROWCNT);    // overlays statp (disjoint lifetime)
    int*    rowbase = (int*)(ws + OFF_ROWBASE);   // dedicated: live until conv2
    float*  pooled1 = (float*)(ws + OFF_POOLED1);
    float*  pooled2 = (float*)(ws + OFF_POOLED2);
    float*  kbuf1   = (float*)(ws + OFF_KBUF1);
    float*  kbuf2   = (float*)(ws + OFF_KBUF2);
    int*    rmap    = (int*)(ws + OFF_RMAP);
    float*  rowsum  = (float*)(ws + OFF_RMAP);   // reuse: rmap dead after scatter
    int*    lists   = (int*)(ws + OFF_LISTS);
    float*  Xt      = (float*)(ws + OFF_XT);
    float*  rawY1   = (float*)(ws + OFF_RAWY1);

    hipLaunchKernelGGL(transpose16_kernel, dim3(HW/256, B_), dim3(256), 0, stream, x, Xt);
    hipLaunchKernelGGL(regionmap_kernel, dim3(H_, B_), dim3(256), 0, stream, hm, rmap, rowcnt);
    hipLaunchKernelGGL(scan2_kernel, dim3(1), dim3(256), 0, stream, rowcnt, offs, rowbase);
    hipLaunchKernelGGL(scatter_kernel, dim3(H_, B_), dim3(256), 0, stream, rmap, rowbase, lists);

    // ---- layer 1 ----
    hipLaunchKernelGGL((rowsum_kernel<CIN1,false>), dim3(H_, B_), dim3(256), 0, stream,
                       Xt, nullptr, nullptr, rowsum);
    hipLaunchKernelGGL((binreduce_kernel<CIN1>), dim3(9, B_), dim3(256), 0, stream,
                       rowsum, pooled1);
    hipLaunchKernelGGL((kgen_kernel<CIN1>), dim3(B_*R_), dim3(256), 0, stream,
                       pooled1, w1_1, b1_1, w2_1, b2_1, kbuf1);
    hipLaunchKernelGGL((conv_kernel<CIN1,1,false,true>), dim3(2, 256), dim3(512), 0, stream,
                       Xt, kbuf1, lists, rowbase, offs, nullptr, nullptr, rawY1);
    hipLaunchKernelGGL(stats_nhwc_kernel, dim3(128), dim3(256), 0, stream, rawY1, statp);
    hipLaunchKernelGGL(bnfinal_kernel, dim3(1), dim3(32), 0, stream, statp, 128, g1, be1, scale1, shift1);

    // ---- layer 2 (BN1+ReLU fused into loads) ----
    hipLaunchKernelGGL((rowsum_kernel<CMID,true>), dim3(H_, B_), dim3(256), 0, stream,
                       rawY1, scale1, shift1, rowsum);
    hipLaunchKernelGGL((binreduce_kernel<CMID>), dim3(9, B_), dim3(256), 0, stream,
                       rowsum, pooled2);
    hipLaunchKernelGGL((kgen_kernel<CMID>), dim3(B_*R_), dim3(256), 0, stream,
                       pooled2, w1_2, b1_2, w2_2, b2_2, kbuf2);
    hipLaunchKernelGGL((conv_kernel<CMID,2,true,false>), dim3(2, 256), dim3(512), 0, stream,
                       rawY1, kbuf2, lists, rowbase, offs, scale1, shift1, out);
    hipLaunchKernelGGL(stats_nchw_kernel, dim3(8, 32), dim3(256), 0, stream, out, statp);
    hipLaunchKernelGGL(bnfinal_kernel, dim3(1), dim3(32), 0, stream, statp, 8, g2, be2, scale2, shift2);
    hipLaunchKernelGGL(eltwise_kernel, dim3((B_*32*HW/4)/256), dim3(256), 0, stream, out, scale2, shift2);
}

// Round 7
// 1308.503 us; speedup vs baseline: 3.7528x; 3.7528x over previous
//
#include <hip/hip_runtime.h>
#include <math.h>

// Problem constants
#define B_    4
#define R_    8
#define H_    256
#define W_    256
#define HW    65536
#define NPIX  (B_*HW)      // 262144
#define CIN1  16
#define CMID  32
#define COUT2 32
#define EPS_  1e-5

// ---------------- workspace layout (bytes) ----------------
#define OFF_OFFSETS  256         // int[33]
#define OFF_SCALE1   768         // float[32]
#define OFF_SHIFT1   896         // float[32]
#define OFF_SCALE2   1024        // float[32]
#define OFF_SHIFT2   1152        // float[32]
#define OFF_STATP    8192        // double[128*32*2] = 65536 B  (overlays rowcnt in setup phase)
#define OFF_ROWCNT   8192        // int[4*256*8] = 32768 B  (dead after scan2, before stats)
#define OFF_ROWBASE  73728       // int[4*256*8] = 32768 B  (LIVE until conv2 - dedicated)
#define OFF_POOLED1  106496      // float[4*16*9]
#define OFF_POOLED2  110592      // float[4*32*9]
#define OFF_KBUF1    139264     // float[147456]   = 589824 B
#define OFF_KBUF2    729088     // float[294912]   = 1179648 B
#define OFF_RMAP     1908736    // int[262144] = 1 MB; dead after scatter -> reused as rowsum
#define OFF_LISTS    2957312    // int[262144]     = 1048576 B
#define OFF_XT       4005888    // float[4*65536*16] = 16777216 B
#define OFF_RAWY1    20783104   // float[4*65536*32] = 33554432 B
// total ~54.3 MB

// ---------------- small setup kernels ----------------

// NCHW (4,16,256,256) -> NHWC (4,65536,16)
__global__ __launch_bounds__(256)
void transpose16_kernel(const float* __restrict__ X, float* __restrict__ Xt) {
    __shared__ float t[16][257];
    const int b   = blockIdx.y;
    const int px0 = blockIdx.x * 256;
    #pragma unroll
    for (int c = 0; c < 16; ++c)
        t[c][threadIdx.x] = X[((size_t)b*16 + c)*HW + px0 + threadIdx.x];
    __syncthreads();
    float4* dst = (float4*)(Xt + ((size_t)b*HW + px0 + threadIdx.x)*16);
    #pragma unroll
    for (int c4 = 0; c4 < 4; ++c4) {
        float4 v;
        v.x = t[c4*4+0][threadIdx.x];
        v.y = t[c4*4+1][threadIdx.x];
        v.z = t[c4*4+2][threadIdx.x];
        v.w = t[c4*4+3][threadIdx.x];
        dst[c4] = v;
    }
}

// One block per image row: argmax over 8 histmap channels -> rmap, per-(b,row,g) counts
__global__ __launch_bounds__(256)
void regionmap_kernel(const float* __restrict__ hm, int* __restrict__ rmap,
                      int* __restrict__ rowcnt) {
    __shared__ int lcnt[8];
    if (threadIdx.x < 8) lcnt[threadIdx.x] = 0;
    __syncthreads();
    const int r = blockIdx.x;
    const int b = blockIdx.y;
    const int pix = r*256 + threadIdx.x;
    const float* hp = hm + (size_t)b*8*HW + pix;
    float best = hp[0]; int g = 0;
    #pragma unroll
    for (int gg = 1; gg < 8; ++gg) {
        float v = hp[(size_t)gg*HW];
        if (v > best) { best = v; g = gg; }
    }
    rmap[(size_t)b*HW + pix] = g;
    atomicAdd(&lcnt[g], 1);
    __syncthreads();
    if (threadIdx.x < 8) rowcnt[((b*H_ + r)<<3) + threadIdx.x] = lcnt[threadIdx.x];
}

// Hierarchical scan: rowcnt -> offs[33] (bucket starts) and rowbase (row segment starts)
__global__ __launch_bounds__(256)
void scan2_kernel(const int* __restrict__ rowcnt, int* __restrict__ offs,
                  int* __restrict__ rowbase) {
    const int tid   = threadIdx.x;
    const int pair  = tid >> 3;   // 0..31 = b*8+g
    const int chunk = tid & 7;    // rows [chunk*32, chunk*32+32)
    const int b = pair >> 3, g = pair & 7;
    __shared__ int ctot[32][8];
    __shared__ int cbase[32][8];
    __shared__ int pstart[33];
    int run = 0;
    #pragma unroll 4
    for (int rr = 0; rr < 32; ++rr) {
        const int r = chunk*32 + rr;
        run += rowcnt[((b*H_ + r)<<3) + g];
    }
    ctot[pair][chunk] = run;
    __syncthreads();
    if (tid < 32) {
        int acc = 0;
        #pragma unroll
        for (int ch = 0; ch < 8; ++ch) { cbase[tid][ch] = acc; acc += ctot[tid][ch]; }
        ctot[tid][0] = acc;  // pair total
    }
    __syncthreads();
    if (tid == 0) {
        int acc = 0;
        for (int pp = 0; pp < 32; ++pp) { pstart[pp] = acc; offs[pp] = acc; acc += ctot[pp][0]; }
        pstart[32] = acc; offs[32] = acc;
    }
    __syncthreads();
    int base = pstart[pair] + cbase[pair][chunk];
    for (int rr = 0; rr < 32; ++rr) {
        const int r = chunk*32 + rr;
        const int idx = ((b*H_ + r)<<3) + g;
        rowbase[idx] = base;
        base += rowcnt[idx];
    }
}

// Row-ordered scatter: lists sorted by row within each (b,g) bucket.
__global__ __launch_bounds__(256)
void scatter_kernel(const int* __restrict__ rmap, const int* __restrict__ rowbase,
                    int* __restrict__ lists) {
    __shared__ int lpos[8];
    const int r = blockIdx.x;
    const int b = blockIdx.y;
    if (threadIdx.x < 8) lpos[threadIdx.x] = rowbase[((b*H_ + r)<<3) + threadIdx.x];
    __syncthreads();
    const int pix = r*256 + threadIdx.x;
    const int g = rmap[(size_t)b*HW + pix];
    const int slot = atomicAdd(&lpos[g], 1);
    lists[slot] = pix;
}

// ---------------- adaptive avg pool, two-stage parallel ----------------
template<int C, bool FUSE>
__global__ __launch_bounds__(256)
void rowsum_kernel(const float* __restrict__ Yin, const float* __restrict__ scale,
                   const float* __restrict__ shift, float* __restrict__ rowsum) {
    constexpr int NS = 256 / C;
    const int h = blockIdx.x;
    const int b = blockIdx.y;
    const int c = threadIdx.x & (C-1);
    float sc = 0.f, sh = 0.f;
    if (FUSE) { sc = scale[c]; sh = shift[c]; }
    const float* row = Yin + ((size_t)b*HW + (size_t)h*W_)*C;
    const int s = threadIdx.x / C;
    float s0 = 0.f, s1 = 0.f, s2 = 0.f;
    for (int w = s; w < W_; w += NS) {
        float v = row[(size_t)w*C + c];
        if (FUSE) v = fmaxf(fmaf(v, sc, sh), 0.f);
        if (w < 86)             s0 += v;
        if (w >= 85 && w < 171) s1 += v;
        if (w >= 170)           s2 += v;
    }
    __shared__ float red[256];
    float* outp = rowsum + (((size_t)b*H_ + h)*3)*C;
    float ss[3] = {s0, s1, s2};
    #pragma unroll
    for (int j = 0; j < 3; ++j) {
        red[threadIdx.x] = ss[j];
        __syncthreads();
        for (int st = 128; st >= C; st >>= 1) {
            if (threadIdx.x < st) red[threadIdx.x] += red[threadIdx.x + st];
            __syncthreads();
        }
        if (threadIdx.x < C) outp[j*C + threadIdx.x] = red[threadIdx.x];
        __syncthreads();
    }
}

template<int C>
__global__ __launch_bounds__(256)
void binreduce_kernel(const float* __restrict__ rowsum, float* __restrict__ pooled) {
    constexpr int NS = 256 / C;
    const int bin = blockIdx.x;          // 0..8
    const int b   = blockIdx.y;
    const int bi = bin/3, bj = bin%3;
    const int h0 = (bi*H_)/3,  h1 = ((bi+1)*H_ + 2)/3;
    const int w0 = (bj*W_)/3,  w1 = ((bj+1)*W_ + 2)/3;
    const int npx = (h1-h0)*(w1-w0);
    const int c = threadIdx.x & (C-1);
    const int s = threadIdx.x / C;
    float sum = 0.f;
    for (int h = h0 + s; h < h1; h += NS)
        sum += rowsum[(((size_t)b*H_ + h)*3 + bj)*C + c];
    __shared__ float red[256];
    red[threadIdx.x] = sum;
    __syncthreads();
    for (int st = 128; st >= C; st >>= 1) {
        if (threadIdx.x < st) red[threadIdx.x] += red[threadIdx.x + st];
        __syncthreads();
    }
    if (threadIdx.x < C)
        pooled[((size_t)b*C + threadIdx.x)*9 + bin] = red[threadIdx.x] / (float)npx;
}

// ---------------- per-sample kernel generation ----------------
// Output layout: kbuf[bg][og2][c][ij][o16]  (contiguous per-(g,og) chunk for staging)
template<int CIN>
__global__ __launch_bounds__(256)
void kgen_kernel(const float* __restrict__ pooled,
                 const float* __restrict__ w1, const float* __restrict__ b1,
                 const float* __restrict__ w2, const float* __restrict__ b2,
                 float* __restrict__ kbuf) {
    __shared__ float t[8][9];
    const int bg = blockIdx.x;
    const int b = bg >> 3, g = bg & 7;
    if (threadIdx.x < 72) {
        const int r = threadIdx.x / 9, ij = threadIdx.x % 9;
        float s = b1[g*8 + r];
        const float* wrow = w1 + (g*8 + r)*CIN;
        const float* prow = pooled + (size_t)b*CIN*9 + ij;
        #pragma unroll
        for (int c = 0; c < CIN; ++c) s += wrow[c] * prow[c*9];
        t[r][ij] = 1.f / (1.f + expf(-s));
    }
    __syncthreads();
    constexpr int TOT = CIN*9*32;
    for (int e = threadIdx.x; e < TOT; e += 256) {
        const int o    = e & 31;
        const int rest = e >> 5;
        const int ij   = rest % 9;
        const int c    = rest / 9;
        const int oc   = o*CIN + c;
        const float* w2row = w2 + ((size_t)g*(CIN*32) + oc)*8;
        float s = b2[(size_t)g*(CIN*32) + oc];
        #pragma unroll
        for (int r = 0; r < 8; ++r) s += w2row[r] * t[r][ij];
        kbuf[(((size_t)bg*2 + (o>>4))*(CIN*9) + (size_t)c*9 + ij)*16 + (o & 15)] = s;
    }
}

// ---------------- main dynamic-region conv (slice-resident, wave-per-region) ----------------
// Block = (slice of 4 rows, og half). 512 threads = 8 waves; wave w owns region g=w.
// Weights for all 8 regions x 16 outs x 16-channel phase in LDS (72 KB, broadcast reads).
// Phase-outer loop: CIN=32 as 2 staged phases, output accumulated via RMW (NCHW path).
// Waves iterate their own bucket segment independently (no lockstep).
template<int CIN, int PHASES, bool FUSE, bool NHWC_OUT>
__global__ __launch_bounds__(512)
void conv_kernel(const float* __restrict__ Xin, const float* __restrict__ kbuf,
                 const int* __restrict__ lists, const int* __restrict__ rowbase,
                 const int* __restrict__ offs,
                 const float* __restrict__ scale, const float* __restrict__ shift,
                 float* __restrict__ Yout) {
    constexpr int PC  = CIN / PHASES;        // 16 channels per phase
    constexpr int C4G = PC*9*16/4;           // float4 per region per phase = 576
    __shared__ __align__(16) float wl[8 * PC*9 * 16];  // 72 KB
    __shared__ float sc[CIN], sh[CIN];
    __shared__ int scnt[8], sbase[8];

    const int s   = blockIdx.x;              // slice 0..255
    const int og  = blockIdx.y;              // 0..1  (id = og*256+s -> same-slice siblings same XCD)
    const int b   = s >> 6;
    const int r0  = (s & 63) * 4;
    const int tid = threadIdx.x;
    const int wave = tid >> 6, lane = tid & 63;

    if (tid < 8) {
        const int st = rowbase[((b*H_ + r0)<<3) + tid];
        const int en = (r0 + 4 < H_) ? rowbase[((b*H_ + r0 + 4)<<3) + tid]
                                     : offs[b*8 + tid + 1];
        sbase[tid] = st; scnt[tid] = en - st;
    }
    if (FUSE && tid < CIN) { sc[tid] = scale[tid]; sh[tid] = shift[tid]; }
    __syncthreads();

    const int g    = wave;
    const int cnt  = scnt[g];
    const int base = sbase[g];
    const int myit = (cnt + 127) >> 7;
    const float* __restrict__ Xb = Xin + (size_t)b * HW * CIN;
    const float4* __restrict__ kb4 = (const float4*)kbuf;
    const int kstride4 = CIN*9*16/4;         // per-(bg,og) chunk in float4

    #pragma unroll 1
    for (int ph = 0; ph < PHASES; ++ph) {
        if (ph) __syncthreads();             // all waves done reading prev phase's wl
        for (int e = tid; e < 8*C4G; e += 512) {
            const int gg = e / C4G, rem = e - gg*C4G;
            ((float4*)wl)[e] = kb4[(size_t)((b*8 + gg)*2 + og)*kstride4 + ph*C4G + rem];
        }
        __syncthreads();

        for (int it = 0; it < myit; ++it) {
            const int ep = (it << 7) + lane;
            const bool val0 = ep < cnt;
            const bool val1 = ep + 64 < cnt;
            int px0 = 0, px1 = 0;
            if (val0) px0 = lists[base + ep];
            if (val1) px1 = lists[base + ep + 64];
            const int h0 = px0 >> 8, w0 = px0 & 255;
            const int h1 = px1 >> 8, w1 = px1 & 255;

            float acc0[16], acc1[16];
            #pragma unroll
            for (int o = 0; o < 16; ++o) { acc0[o] = 0.f; acc1[o] = 0.f; }

            #pragma unroll 1
            for (int di = -1; di <= 1; ++di) {
                #pragma unroll 1
                for (int dj = -1; dj <= 1; ++dj) {
                    const int ij = (di+1)*3 + (dj+1);
                    const bool v0 = val0 && ((unsigned)(h0+di) < (unsigned)H_) && ((unsigned)(w0+dj) < (unsigned)W_);
                    const bool v1 = val1 && ((unsigned)(h1+di) < (unsigned)H_) && ((unsigned)(w1+dj) < (unsigned)W_);
                    const float* r0p = Xb + (long)(px0 + di*W_ + dj)*CIN + ph*PC;
                    const float* r1p = Xb + (long)(px1 + di*W_ + dj)*CIN + ph*PC;
                    #pragma unroll
                    for (int c4 = 0; c4 < PC/4; ++c4) {
                        float4 x0 = make_float4(0.f,0.f,0.f,0.f);
                        float4 x1 = make_float4(0.f,0.f,0.f,0.f);
                        if (v0) {
                            x0 = *(const float4*)(r0p + (c4<<2));
                            if (FUSE) {
                                const int cb = ph*PC + (c4<<2);
                                x0.x = fmaxf(fmaf(x0.x, sc[cb+0], sh[cb+0]), 0.f);
                                x0.y = fmaxf(fmaf(x0.y, sc[cb+1], sh[cb+1]), 0.f);
                                x0.z = fmaxf(fmaf(x0.z, sc[cb+2], sh[cb+2]), 0.f);
                                x0.w = fmaxf(fmaf(x0.w, sc[cb+3], sh[cb+3]), 0.f);
                            }
                        }
                        if (v1) {
                            x1 = *(const float4*)(r1p + (c4<<2));
                            if (FUSE) {
                                const int cb = ph*PC + (c4<<2);
                                x1.x = fmaxf(fmaf(x1.x, sc[cb+0], sh[cb+0]), 0.f);
                                x1.y = fmaxf(fmaf(x1.y, sc[cb+1], sh[cb+1]), 0.f);
                                x1.z = fmaxf(fmaf(x1.z, sc[cb+2], sh[cb+2]), 0.f);
                                x1.w = fmaxf(fmaf(x1.w, sc[cb+3], sh[cb+3]), 0.f);
                            }
                        }
                        #pragma unroll
                        for (int k = 0; k < 4; ++k) {
                            const float xa = (k==0)?x0.x:((k==1)?x0.y:((k==2)?x0.z:x0.w));
                            const float xb = (k==0)?x1.x:((k==1)?x1.y:((k==2)?x1.z:x1.w));
                            // wave-uniform address -> LDS broadcast, conflict-free
                            const float4* wrow = (const float4*)&wl[((size_t)g*(PC*9) + ((c4<<2)+k)*9 + ij)*16];
                            #pragma unroll
                            for (int o4 = 0; o4 < 4; ++o4) {
                                const float4 w4 = wrow[o4];
                                acc0[o4*4+0] = fmaf(xa, w4.x, acc0[o4*4+0]);
                                acc0[o4*4+1] = fmaf(xa, w4.y, acc0[o4*4+1]);
                                acc0[o4*4+2] = fmaf(xa, w4.z, acc0[o4*4+2]);
                                acc0[o4*4+3] = fmaf(xa, w4.w, acc0[o4*4+3]);
                                acc1[o4*4+0] = fmaf(xb, w4.x, acc1[o4*4+0]);
                                acc1[o4*4+1] = fmaf(xb, w4.y, acc1[o4*4+1]);
                                acc1[o4*4+2] = fmaf(xb, w4.z, acc1[o4*4+2]);
                                acc1[o4*4+3] = fmaf(xb, w4.w, acc1[o4*4+3]);
                            }
                        }
                    }
                }
            }

            if (NHWC_OUT) {
                if (val0) {
                    float4* d = (float4*)(Yout + ((size_t)b*HW + px0)*32 + og*16);
                    #pragma unroll
                    for (int o4 = 0; o4 < 4; ++o4)
                        d[o4] = make_float4(acc0[o4*4+0], acc0[o4*4+1], acc0[o4*4+2], acc0[o4*4+3]);
                }
                if (val1) {
                    float4* d = (float4*)(Yout + ((size_t)b*HW + px1)*32 + og*16);
                    #pragma unroll
                    for (int o4 = 0; o4 < 4; ++o4)
                        d[o4] = make_float4(acc1[o4*4+0], acc1[o4*4+1], acc1[o4*4+2], acc1[o4*4+3]);
                }
            } else {
                if (val0) {
                    float* d = Yout + ((size_t)b*32 + og*16)*HW + px0;
                    if (ph == 0) {
                        #pragma unroll
                        for (int o = 0; o < 16; ++o) d[(size_t)o*HW] = acc0[o];
                    } else {
                        #pragma unroll
                        for (int o = 0; o < 16; ++o) d[(size_t)o*HW] += acc0[o];
                    }
                }
                if (val1) {
                    float* d = Yout + ((size_t)b*32 + og*16)*HW + px1;
                    if (ph == 0) {
                        #pragma unroll
                        for (int o = 0; o < 16; ++o) d[(size_t)o*HW] = acc1[o];
                    } else {
                        #pragma unroll
                        for (int o = 0; o < 16; ++o) d[(size_t)o*HW] += acc1[o];
                    }
                }
            }
        }
    }
}

// ---------------- BN statistics ----------------
// NHWC (B,HW,32): 128 blocks x 2048 pixels
__global__ __launch_bounds__(256)
void stats_nhwc_kernel(const float* __restrict__ Y, double* __restrict__ statp) {
    const int c = threadIdx.x & 31;
    const int s = threadIdx.x >> 5;  // 0..7
    const int p0 = blockIdx.x * 2048;
    double sum = 0.0, sq = 0.0;
    for (int p = p0 + s; p < p0 + 2048; p += 8) {
        const float v = Y[(size_t)p*32 + c];
        sum += v; sq += (double)v*v;
    }
    __shared__ double rs[256], rq[256];
    rs[threadIdx.x] = sum; rq[threadIdx.x] = sq;
    __syncthreads();
    for (int st = 128; st >= 32; st >>= 1) {
        if (threadIdx.x < st) { rs[threadIdx.x] += rs[threadIdx.x+st]; rq[threadIdx.x] += rq[threadIdx.x+st]; }
        __syncthreads();
    }
    if (threadIdx.x < 32) {
        statp[((size_t)blockIdx.x*32 + threadIdx.x)*2 + 0] = rs[threadIdx.x];
        statp[((size_t)blockIdx.x*32 + threadIdx.x)*2 + 1] = rq[threadIdx.x];
    }
}

__global__ __launch_bounds__(256)
void stats_nchw_kernel(const float* __restrict__ Y, double* __restrict__ statp) {
    const int co = blockIdx.y, chunk = blockIdx.x;
    double sum = 0.0, sq = 0.0;
    for (int b = 0; b < B_; ++b) {
        const float* base = Y + ((size_t)b*32 + co)*HW + chunk*8192;
        for (int k = threadIdx.x; k < 8192; k += 256) {
            const float v = base[k];
            sum += v; sq += (double)v*v;
        }
    }
    __shared__ double rs[256], rq[256];
    rs[threadIdx.x] = sum; rq[threadIdx.x] = sq;
    __syncthreads();
    for (int st = 128; st >= 1; st >>= 1) {
        if (threadIdx.x < st) { rs[threadIdx.x] += rs[threadIdx.x+st]; rq[threadIdx.x] += rq[threadIdx.x+st]; }
        __syncthreads();
    }
    if (threadIdx.x == 0) {
        statp[((size_t)chunk*32 + co)*2 + 0] = rs[0];
        statp[((size_t)chunk*32 + co)*2 + 1] = rq[0];
    }
}

__global__ void bnfinal_kernel(const double* __restrict__ statp, int nblk,
                               const float* __restrict__ gamma, const float* __restrict__ beta,
                               float* __restrict__ scale, float* __restrict__ shift) {
    const int c = threadIdx.x;
    if (c < 32) {
        double s = 0.0, q = 0.0;
        for (int k = 0; k < nblk; ++k) {
            s += statp[((size_t)k*32 + c)*2 + 0];
            q += statp[((size_t)k*32 + c)*2 + 1];
        }
        const double N = (double)NPIX;
        const double mean = s / N;
        const double var  = q / N - mean*mean;
        const double inv  = 1.0 / sqrt(var + EPS_);
        scale[c] = (float)((double)gamma[c] * inv);
        shift[c] = (float)((double)beta[c] - mean * (double)gamma[c] * inv);
    }
}

__global__ __launch_bounds__(256)
void eltwise_kernel(float* __restrict__ Y, const float* __restrict__ scale,
                    const float* __restrict__ shift) {
    const int idx = blockIdx.x*256 + threadIdx.x;        // float4 index
    const int c = (idx >> 14) & 31;
    const float s = scale[c], sh = shift[c];
    float4 v = ((float4*)Y)[idx];
    v.x = fmaxf(fmaf(v.x, s, sh), 0.f);
    v.y = fmaxf(fmaf(v.y, s, sh), 0.f);
    v.z = fmaxf(fmaf(v.z, s, sh), 0.f);
    v.w = fmaxf(fmaf(v.w, s, sh), 0.f);
    ((float4*)Y)[idx] = v;
}

// ---------------- launcher ----------------
extern "C" void kernel_launch(void* const* d_in, const int* in_sizes, int n_in,
                              void* d_out, int out_size, void* d_ws, size_t ws_size,
                              hipStream_t stream) {
    const float* x    = (const float*)d_in[0];
    const float* hm   = (const float*)d_in[1];
    const float* w1_1 = (const float*)d_in[2];
    const float* b1_1 = (const float*)d_in[3];
    const float* w2_1 = (const float*)d_in[4];
    const float* b2_1 = (const float*)d_in[5];
    const float* g1   = (const float*)d_in[6];
    const float* be1  = (const float*)d_in[7];
    const float* w1_2 = (const float*)d_in[8];
    const float* b1_2 = (const float*)d_in[9];
    const float* w2_2 = (const float*)d_in[10];
    const float* b2_2 = (const float*)d_in[11];
    const float* g2   = (const float*)d_in[12];
    const float* be2  = (const float*)d_in[13];
    float* out = (float*)d_out;

    char* ws = (char*)d_ws;
    int*    offs    = (int*)(ws + OFF_OFFSETS);
    float*  scale1  = (float*)(ws + OFF_SCALE1);
    float*  shift1  = (float*)(ws + OFF_SHIFT1);
    float*  scale2  = (float*)(ws + OFF_SCALE2);
    float*  shift2  = (float*)(ws + OFF_SHIFT2);
    double* statp   = (double*)(ws + OFF_STATP);
    int*    rowcnt  = (int*)(ws + OFF_ROWCNT);    // overlays statp (disjoint lifetime)
    int*    rowbase = (int*)(ws + OFF_ROWBASE);   // dedicated: live until conv2
    float*  pooled1 = (float*)(ws + OFF_POOLED1);
    float*  pooled2 = (float*)(ws + OFF_POOLED2);
    float*  kbuf1   = (float*)(ws + OFF_KBUF1);
    float*  kbuf2   = (float*)(ws + OFF_KBUF2);
    int*    rmap    = (int*)(ws + OFF_RMAP);
    float*  rowsum  = (float*)(ws + OFF_RMAP);   // reuse: rmap dead after scatter
    int*    lists   = (int*)(ws + OFF_LISTS);
    float*  Xt      = (float*)(ws + OFF_XT);
    float*  rawY1   = (float*)(ws + OFF_RAWY1);

    hipLaunchKernelGGL(transpose16_kernel, dim3(HW/256, B_), dim3(256), 0, stream, x, Xt);
    hipLaunchKernelGGL(regionmap_kernel, dim3(H_, B_), dim3(256), 0, stream, hm, rmap, rowcnt);
    hipLaunchKernelGGL(scan2_kernel, dim3(1), dim3(256), 0, stream, rowcnt, offs, rowbase);
    hipLaunchKernelGGL(scatter_kernel, dim3(H_, B_), dim3(256), 0, stream, rmap, rowbase, lists);

    // ---- layer 1 ----
    hipLaunchKernelGGL((rowsum_kernel<CIN1,false>), dim3(H_, B_), dim3(256), 0, stream,
                       Xt, nullptr, nullptr, rowsum);
    hipLaunchKernelGGL((binreduce_kernel<CIN1>), dim3(9, B_), dim3(256), 0, stream,
                       rowsum, pooled1);
    hipLaunchKernelGGL((kgen_kernel<CIN1>), dim3(B_*R_), dim3(256), 0, stream,
                       pooled1, w1_1, b1_1, w2_1, b2_1, kbuf1);
    hipLaunchKernelGGL((conv_kernel<CIN1,1,false,true>), dim3(256, 2), dim3(512), 0, stream,
                       Xt, kbuf1, lists, rowbase, offs, nullptr, nullptr, rawY1);
    hipLaunchKernelGGL(stats_nhwc_kernel, dim3(128), dim3(256), 0, stream, rawY1, statp);
    hipLaunchKernelGGL(bnfinal_kernel, dim3(1), dim3(32), 0, stream, statp, 128, g1, be1, scale1, shift1);

    // ---- layer 2 (BN1+ReLU fused into loads) ----
    hipLaunchKernelGGL((rowsum_kernel<CMID,true>), dim3(H_, B_), dim3(256), 0, stream,
                       rawY1, scale1, shift1, rowsum);
    hipLaunchKernelGGL((binreduce_kernel<CMID>), dim3(9, B_), dim3(256), 0, stream,
                       rowsum, pooled2);
    hipLaunchKernelGGL((kgen_kernel<CMID>), dim3(B_*R_), dim3(256), 0, stream,
                       pooled2, w1_2, b1_2, w2_2, b2_2, kbuf2);
    hipLaunchKernelGGL((conv_kernel<CMID,2,true,false>), dim3(256, 2), dim3(512), 0, stream,
                       rawY1, kbuf2, lists, rowbase, offs, scale1, shift1, out);
    hipLaunchKernelGGL(stats_nchw_kernel, dim3(8, 32), dim3(256), 0, stream, out, statp);
    hipLaunchKernelGGL(bnfinal_kernel, dim3(1), dim3(32), 0, stream, statp, 8, g2, be2, scale2, shift2);
    hipLaunchKernelGGL(eltwise_kernel, dim3((B_*32*HW/4)/256), dim3(256), 0, stream, out, scale2, shift2);
}

// Round 8
// 574.175 us; speedup vs baseline: 8.5524x; 2.2789x over previous
//
#include <hip/hip_runtime.h>
#include <math.h>

// Problem constants
#define B_    4
#define R_    8
#define H_    256
#define W_    256
#define HW    65536
#define NPIX  (B_*HW)      // 262144
#define CIN1  16
#define CMID  32
#define COUT2 32
#define EPS_  1e-5

// ---------------- workspace layout (bytes) ----------------
#define OFF_OFFSETS  256         // int[33]
#define OFF_SCALE1   768         // float[32]
#define OFF_SHIFT1   896         // float[32]
#define OFF_SCALE2   1024        // float[32]
#define OFF_SHIFT2   1152        // float[32]
#define OFF_STATP    8192        // double[128*32*2] = 65536 B  (overlays rowcnt in setup phase)
#define OFF_ROWCNT   8192        // int[4*256*8] = 32768 B  (dead after scan2, before stats)
#define OFF_ROWBASE  73728       // int[4*256*8] = 32768 B
#define OFF_POOLED1  106496      // float[4*16*9]
#define OFF_POOLED2  110592      // float[4*32*9]
#define OFF_KBUF1    139264     // float[147456]   = 589824 B
#define OFF_KBUF2    729088     // float[294912]   = 1179648 B
#define OFF_RMAP     1908736    // int[262144] = 1 MB; dead after scatter -> reused as rowsum
#define OFF_LISTS    2957312    // int[262144]     = 1048576 B
#define OFF_XT       4005888    // float[4*65536*16] = 16777216 B
#define OFF_RAWY1    20783104   // float[4*65536*32] = 33554432 B
// total ~54.3 MB

// ---------------- small setup kernels ----------------

// NCHW (4,16,256,256) -> NHWC (4,65536,16)
__global__ __launch_bounds__(256)
void transpose16_kernel(const float* __restrict__ X, float* __restrict__ Xt) {
    __shared__ float t[16][257];
    const int b   = blockIdx.y;
    const int px0 = blockIdx.x * 256;
    #pragma unroll
    for (int c = 0; c < 16; ++c)
        t[c][threadIdx.x] = X[((size_t)b*16 + c)*HW + px0 + threadIdx.x];
    __syncthreads();
    float4* dst = (float4*)(Xt + ((size_t)b*HW + px0 + threadIdx.x)*16);
    #pragma unroll
    for (int c4 = 0; c4 < 4; ++c4) {
        float4 v;
        v.x = t[c4*4+0][threadIdx.x];
        v.y = t[c4*4+1][threadIdx.x];
        v.z = t[c4*4+2][threadIdx.x];
        v.w = t[c4*4+3][threadIdx.x];
        dst[c4] = v;
    }
}

// One block per image row: argmax over 8 histmap channels -> rmap, per-(b,row,g) counts
__global__ __launch_bounds__(256)
void regionmap_kernel(const float* __restrict__ hm, int* __restrict__ rmap,
                      int* __restrict__ rowcnt) {
    __shared__ int lcnt[8];
    if (threadIdx.x < 8) lcnt[threadIdx.x] = 0;
    __syncthreads();
    const int r = blockIdx.x;
    const int b = blockIdx.y;
    const int pix = r*256 + threadIdx.x;
    const float* hp = hm + (size_t)b*8*HW + pix;
    float best = hp[0]; int g = 0;
    #pragma unroll
    for (int gg = 1; gg < 8; ++gg) {
        float v = hp[(size_t)gg*HW];
        if (v > best) { best = v; g = gg; }
    }
    rmap[(size_t)b*HW + pix] = g;
    atomicAdd(&lcnt[g], 1);
    __syncthreads();
    if (threadIdx.x < 8) rowcnt[((b*H_ + r)<<3) + threadIdx.x] = lcnt[threadIdx.x];
}

// Hierarchical scan: rowcnt -> offs[33] (bucket starts) and rowbase (row segment starts)
__global__ __launch_bounds__(256)
void scan2_kernel(const int* __restrict__ rowcnt, int* __restrict__ offs,
                  int* __restrict__ rowbase) {
    const int tid   = threadIdx.x;
    const int pair  = tid >> 3;   // 0..31 = b*8+g
    const int chunk = tid & 7;    // rows [chunk*32, chunk*32+32)
    const int b = pair >> 3, g = pair & 7;
    __shared__ int ctot[32][8];
    __shared__ int cbase[32][8];
    __shared__ int pstart[33];
    int run = 0;
    #pragma unroll 4
    for (int rr = 0; rr < 32; ++rr) {
        const int r = chunk*32 + rr;
        run += rowcnt[((b*H_ + r)<<3) + g];
    }
    ctot[pair][chunk] = run;
    __syncthreads();
    if (tid < 32) {
        int acc = 0;
        #pragma unroll
        for (int ch = 0; ch < 8; ++ch) { cbase[tid][ch] = acc; acc += ctot[tid][ch]; }
        ctot[tid][0] = acc;  // pair total
    }
    __syncthreads();
    if (tid == 0) {
        int acc = 0;
        for (int pp = 0; pp < 32; ++pp) { pstart[pp] = acc; offs[pp] = acc; acc += ctot[pp][0]; }
        pstart[32] = acc; offs[32] = acc;
    }
    __syncthreads();
    int base = pstart[pair] + cbase[pair][chunk];
    for (int rr = 0; rr < 32; ++rr) {
        const int r = chunk*32 + rr;
        const int idx = ((b*H_ + r)<<3) + g;
        rowbase[idx] = base;
        base += rowcnt[idx];
    }
}

// Row-ordered scatter: lists sorted by row within each (b,g) bucket.
__global__ __launch_bounds__(256)
void scatter_kernel(const int* __restrict__ rmap, const int* __restrict__ rowbase,
                    int* __restrict__ lists) {
    __shared__ int lpos[8];
    const int r = blockIdx.x;
    const int b = blockIdx.y;
    if (threadIdx.x < 8) lpos[threadIdx.x] = rowbase[((b*H_ + r)<<3) + threadIdx.x];
    __syncthreads();
    const int pix = r*256 + threadIdx.x;
    const int g = rmap[(size_t)b*HW + pix];
    const int slot = atomicAdd(&lpos[g], 1);
    lists[slot] = pix;
}

// ---------------- adaptive avg pool, two-stage parallel ----------------
template<int C, bool FUSE>
__global__ __launch_bounds__(256)
void rowsum_kernel(const float* __restrict__ Yin, const float* __restrict__ scale,
                   const float* __restrict__ shift, float* __restrict__ rowsum) {
    constexpr int NS = 256 / C;
    const int h = blockIdx.x;
    const int b = blockIdx.y;
    const int c = threadIdx.x & (C-1);
    float sc = 0.f, sh = 0.f;
    if (FUSE) { sc = scale[c]; sh = shift[c]; }
    const float* row = Yin + ((size_t)b*HW + (size_t)h*W_)*C;
    const int s = threadIdx.x / C;
    float s0 = 0.f, s1 = 0.f, s2 = 0.f;
    for (int w = s; w < W_; w += NS) {
        float v = row[(size_t)w*C + c];
        if (FUSE) v = fmaxf(fmaf(v, sc, sh), 0.f);
        if (w < 86)             s0 += v;
        if (w >= 85 && w < 171) s1 += v;
        if (w >= 170)           s2 += v;
    }
    __shared__ float red[256];
    float* outp = rowsum + (((size_t)b*H_ + h)*3)*C;
    float ss[3] = {s0, s1, s2};
    #pragma unroll
    for (int j = 0; j < 3; ++j) {
        red[threadIdx.x] = ss[j];
        __syncthreads();
        for (int st = 128; st >= C; st >>= 1) {
            if (threadIdx.x < st) red[threadIdx.x] += red[threadIdx.x + st];
            __syncthreads();
        }
        if (threadIdx.x < C) outp[j*C + threadIdx.x] = red[threadIdx.x];
        __syncthreads();
    }
}

template<int C>
__global__ __launch_bounds__(256)
void binreduce_kernel(const float* __restrict__ rowsum, float* __restrict__ pooled) {
    constexpr int NS = 256 / C;
    const int bin = blockIdx.x;          // 0..8
    const int b   = blockIdx.y;
    const int bi = bin/3, bj = bin%3;
    const int h0 = (bi*H_)/3,  h1 = ((bi+1)*H_ + 2)/3;
    const int w0 = (bj*W_)/3,  w1 = ((bj+1)*W_ + 2)/3;
    const int npx = (h1-h0)*(w1-w0);
    const int c = threadIdx.x & (C-1);
    const int s = threadIdx.x / C;
    float sum = 0.f;
    for (int h = h0 + s; h < h1; h += NS)
        sum += rowsum[(((size_t)b*H_ + h)*3 + bj)*C + c];
    __shared__ float red[256];
    red[threadIdx.x] = sum;
    __syncthreads();
    for (int st = 128; st >= C; st >>= 1) {
        if (threadIdx.x < st) red[threadIdx.x] += red[threadIdx.x + st];
        __syncthreads();
    }
    if (threadIdx.x < C)
        pooled[((size_t)b*C + threadIdx.x)*9 + bin] = red[threadIdx.x] / (float)npx;
}

// ---------------- per-sample kernel generation ----------------
// Layout: kbuf[bg][(c*9+ij)*32 + o]  (R2 layout - contiguous per bucket)
template<int CIN>
__global__ __launch_bounds__(256)
void kgen_kernel(const float* __restrict__ pooled,
                 const float* __restrict__ w1, const float* __restrict__ b1,
                 const float* __restrict__ w2, const float* __restrict__ b2,
                 float* __restrict__ kbuf) {
    __shared__ float t[8][9];
    const int bg = blockIdx.x;
    const int b = bg >> 3, g = bg & 7;
    if (threadIdx.x < 72) {
        const int r = threadIdx.x / 9, ij = threadIdx.x % 9;
        float s = b1[g*8 + r];
        const float* wrow = w1 + (g*8 + r)*CIN;
        const float* prow = pooled + (size_t)b*CIN*9 + ij;
        #pragma unroll
        for (int c = 0; c < CIN; ++c) s += wrow[c] * prow[c*9];
        t[r][ij] = 1.f / (1.f + expf(-s));
    }
    __syncthreads();
    constexpr int TOT = CIN*9*32;
    for (int e = threadIdx.x; e < TOT; e += 256) {
        const int o    = e & 31;
        const int rest = e >> 5;
        const int ij   = rest % 9;
        const int c    = rest / 9;
        const int oc   = o*CIN + c;
        const float* w2row = w2 + ((size_t)g*(CIN*32) + oc)*8;
        float s = b2[(size_t)g*(CIN*32) + oc];
        #pragma unroll
        for (int r = 0; r < 8; ++r) s += w2row[r] * t[r][ij];
        kbuf[(size_t)bg*TOT + e] = s;
    }
}

// ---------------- main dynamic-region conv ----------------
// R2 structure + row-sorted lists + XCD-aligned contiguous chunks.
// Block = (chunk cx of 16, bucket bg of 32); 256 threads; one region's weights in
// LDS (wave-uniform broadcast reads); 2-px ILP at (i, i+256) with per-chunk ~512
// entries so both pixels are live. Linear block id = cx + 16*bg => all buckets'
// chunk-cx blocks share id%8 (same-XCD L2 window sharing heuristic).
template<int CIN, bool FUSE, bool NHWC_OUT>
__global__ __launch_bounds__(256)
void conv_kernel(const float* __restrict__ Xin, const float* __restrict__ kbuf,
                 const int* __restrict__ lists, const int* __restrict__ offs,
                 const float* __restrict__ scale, const float* __restrict__ shift,
                 float* __restrict__ Yout) {
    constexpr int WSZ = CIN*9*32;
    __shared__ __align__(16) float wlds[WSZ];
    __shared__ float sc[CIN], sh[CIN];
    const int bg = blockIdx.y;
    const int b  = bg >> 3;
    {
        const float4* kb4 = (const float4*)(kbuf + (size_t)bg * WSZ);
        for (int e = threadIdx.x; e < WSZ/4; e += 256) ((float4*)wlds)[e] = kb4[e];
        if (FUSE) for (int c = threadIdx.x; c < CIN; c += 256) { sc[c] = scale[c]; sh[c] = shift[c]; }
    }
    __syncthreads();
    const int start = offs[bg], end = offs[bg+1];
    const int cnt = end - start;
    const int per = (cnt + (int)gridDim.x - 1) / (int)gridDim.x;
    const int i0  = start + (int)blockIdx.x * per;
    const int i1  = min(i0 + per, end);
    const float* __restrict__ Xb = Xin + (size_t)b * HW * CIN;
    for (int i = i0 + (int)threadIdx.x; i < i1; i += 512) {
        const int i2  = i + 256;
        const bool has2 = (i2 < i1);
        const int pix1 = lists[i];
        const int pix2 = has2 ? lists[i2] : pix1;
        const int h1 = pix1 >> 8, ww1 = pix1 & 255;
        const int h2 = pix2 >> 8, ww2 = pix2 & 255;
        float acc1[32], acc2[32];
        #pragma unroll
        for (int o = 0; o < 32; ++o) { acc1[o] = 0.f; acc2[o] = 0.f; }

        #pragma unroll 1
        for (int di = -1; di <= 1; ++di) {
            #pragma unroll 1
            for (int dj = -1; dj <= 1; ++dj) {
                const int ij = (di+1)*3 + (dj+1);
                const bool v1 = ((unsigned)(h1+di) < (unsigned)H_) && ((unsigned)(ww1+dj) < (unsigned)W_);
                const bool v2 = has2 && ((unsigned)(h2+di) < (unsigned)H_) && ((unsigned)(ww2+dj) < (unsigned)W_);
                const float* row1 = Xb + (long)(pix1 + di*W_ + dj) * CIN;
                const float* row2 = Xb + (long)(pix2 + di*W_ + dj) * CIN;
                #pragma unroll 1
                for (int c4 = 0; c4 < CIN/4; ++c4) {
                    float4 x1 = make_float4(0.f,0.f,0.f,0.f);
                    float4 x2 = make_float4(0.f,0.f,0.f,0.f);
                    if (v1) {
                        x1 = *(const float4*)(row1 + (c4<<2));
                        if (FUSE) {
                            x1.x = fmaxf(fmaf(x1.x, sc[(c4<<2)+0], sh[(c4<<2)+0]), 0.f);
                            x1.y = fmaxf(fmaf(x1.y, sc[(c4<<2)+1], sh[(c4<<2)+1]), 0.f);
                            x1.z = fmaxf(fmaf(x1.z, sc[(c4<<2)+2], sh[(c4<<2)+2]), 0.f);
                            x1.w = fmaxf(fmaf(x1.w, sc[(c4<<2)+3], sh[(c4<<2)+3]), 0.f);
                        }
                    }
                    if (v2) {
                        x2 = *(const float4*)(row2 + (c4<<2));
                        if (FUSE) {
                            x2.x = fmaxf(fmaf(x2.x, sc[(c4<<2)+0], sh[(c4<<2)+0]), 0.f);
                            x2.y = fmaxf(fmaf(x2.y, sc[(c4<<2)+1], sh[(c4<<2)+1]), 0.f);
                            x2.z = fmaxf(fmaf(x2.z, sc[(c4<<2)+2], sh[(c4<<2)+2]), 0.f);
                            x2.w = fmaxf(fmaf(x2.w, sc[(c4<<2)+3], sh[(c4<<2)+3]), 0.f);
                        }
                    }
                    #pragma unroll
                    for (int k = 0; k < 4; ++k) {
                        const float xa = (k==0)?x1.x:((k==1)?x1.y:((k==2)?x1.z:x1.w));
                        const float xb = (k==0)?x2.x:((k==1)?x2.y:((k==2)?x2.z:x2.w));
                        // wave-uniform address -> LDS broadcast, conflict-free
                        const float4* wrow = (const float4*)&wlds[(((c4<<2)+k)*9 + ij)*32];
                        #pragma unroll
                        for (int o4 = 0; o4 < 8; ++o4) {
                            const float4 w4 = wrow[o4];
                            acc1[o4*4+0] = fmaf(xa, w4.x, acc1[o4*4+0]);
                            acc1[o4*4+1] = fmaf(xa, w4.y, acc1[o4*4+1]);
                            acc1[o4*4+2] = fmaf(xa, w4.z, acc1[o4*4+2]);
                            acc1[o4*4+3] = fmaf(xa, w4.w, acc1[o4*4+3]);
                            acc2[o4*4+0] = fmaf(xb, w4.x, acc2[o4*4+0]);
                            acc2[o4*4+1] = fmaf(xb, w4.y, acc2[o4*4+1]);
                            acc2[o4*4+2] = fmaf(xb, w4.z, acc2[o4*4+2]);
                            acc2[o4*4+3] = fmaf(xb, w4.w, acc2[o4*4+3]);
                        }
                    }
                }
            }
        }

        if (NHWC_OUT) {
            float4* dst1 = (float4*)(Yout + ((size_t)b*HW + pix1)*32);
            #pragma unroll
            for (int o4 = 0; o4 < 8; ++o4)
                dst1[o4] = make_float4(acc1[o4*4+0], acc1[o4*4+1], acc1[o4*4+2], acc1[o4*4+3]);
            if (has2) {
                float4* dst2 = (float4*)(Yout + ((size_t)b*HW + pix2)*32);
                #pragma unroll
                for (int o4 = 0; o4 < 8; ++o4)
                    dst2[o4] = make_float4(acc2[o4*4+0], acc2[o4*4+1], acc2[o4*4+2], acc2[o4*4+3]);
            }
        } else {
            float* dst1 = Yout + (size_t)b*32*HW + pix1;
            #pragma unroll
            for (int o = 0; o < 32; ++o) dst1[(size_t)o*HW] = acc1[o];
            if (has2) {
                float* dst2 = Yout + (size_t)b*32*HW + pix2;
                #pragma unroll
                for (int o = 0; o < 32; ++o) dst2[(size_t)o*HW] = acc2[o];
            }
        }
    }
}

// ---------------- BN statistics ----------------
// NHWC (B,HW,32): 128 blocks x 2048 pixels
__global__ __launch_bounds__(256)
void stats_nhwc_kernel(const float* __restrict__ Y, double* __restrict__ statp) {
    const int c = threadIdx.x & 31;
    const int s = threadIdx.x >> 5;  // 0..7
    const int p0 = blockIdx.x * 2048;
    double sum = 0.0, sq = 0.0;
    for (int p = p0 + s; p < p0 + 2048; p += 8) {
        const float v = Y[(size_t)p*32 + c];
        sum += v; sq += (double)v*v;
    }
    __shared__ double rs[256], rq[256];
    rs[threadIdx.x] = sum; rq[threadIdx.x] = sq;
    __syncthreads();
    for (int st = 128; st >= 32; st >>= 1) {
        if (threadIdx.x < st) { rs[threadIdx.x] += rs[threadIdx.x+st]; rq[threadIdx.x] += rq[threadIdx.x+st]; }
        __syncthreads();
    }
    if (threadIdx.x < 32) {
        statp[((size_t)blockIdx.x*32 + threadIdx.x)*2 + 0] = rs[threadIdx.x];
        statp[((size_t)blockIdx.x*32 + threadIdx.x)*2 + 1] = rq[threadIdx.x];
    }
}

__global__ __launch_bounds__(256)
void stats_nchw_kernel(const float* __restrict__ Y, double* __restrict__ statp) {
    const int co = blockIdx.y, chunk = blockIdx.x;
    double sum = 0.0, sq = 0.0;
    for (int b = 0; b < B_; ++b) {
        const float* base = Y + ((size_t)b*32 + co)*HW + chunk*8192;
        for (int k = threadIdx.x; k < 8192; k += 256) {
            const float v = base[k];
            sum += v; sq += (double)v*v;
        }
    }
    __shared__ double rs[256], rq[256];
    rs[threadIdx.x] = sum; rq[threadIdx.x] = sq;
    __syncthreads();
    for (int st = 128; st >= 1; st >>= 1) {
        if (threadIdx.x < st) { rs[threadIdx.x] += rs[threadIdx.x+st]; rq[threadIdx.x] += rq[threadIdx.x+st]; }
        __syncthreads();
    }
    if (threadIdx.x == 0) {
        statp[((size_t)chunk*32 + co)*2 + 0] = rs[0];
        statp[((size_t)chunk*32 + co)*2 + 1] = rq[0];
    }
}

__global__ void bnfinal_kernel(const double* __restrict__ statp, int nblk,
                               const float* __restrict__ gamma, const float* __restrict__ beta,
                               float* __restrict__ scale, float* __restrict__ shift) {
    const int c = threadIdx.x;
    if (c < 32) {
        double s = 0.0, q = 0.0;
        for (int k = 0; k < nblk; ++k) {
            s += statp[((size_t)k*32 + c)*2 + 0];
            q += statp[((size_t)k*32 + c)*2 + 1];
        }
        const double N = (double)NPIX;
        const double mean = s / N;
        const double var  = q / N - mean*mean;
        const double inv  = 1.0 / sqrt(var + EPS_);
        scale[c] = (float)((double)gamma[c] * inv);
        shift[c] = (float)((double)beta[c] - mean * (double)gamma[c] * inv);
    }
}

__global__ __launch_bounds__(256)
void eltwise_kernel(float* __restrict__ Y, const float* __restrict__ scale,
                    const float* __restrict__ shift) {
    const int idx = blockIdx.x*256 + threadIdx.x;        // float4 index
    const int c = (idx >> 14) & 31;
    const float s = scale[c], sh = shift[c];
    float4 v = ((float4*)Y)[idx];
    v.x = fmaxf(fmaf(v.x, s, sh), 0.f);
    v.y = fmaxf(fmaf(v.y, s, sh), 0.f);
    v.z = fmaxf(fmaf(v.z, s, sh), 0.f);
    v.w = fmaxf(fmaf(v.w, s, sh), 0.f);
    ((float4*)Y)[idx] = v;
}

// ---------------- launcher ----------------
extern "C" void kernel_launch(void* const* d_in, const int* in_sizes, int n_in,
                              void* d_out, int out_size, void* d_ws, size_t ws_size,
                              hipStream_t stream) {
    const float* x    = (const float*)d_in[0];
    const float* hm   = (const float*)d_in[1];
    const float* w1_1 = (const float*)d_in[2];
    const float* b1_1 = (const float*)d_in[3];
    const float* w2_1 = (const float*)d_in[4];
    const float* b2_1 = (const float*)d_in[5];
    const float* g1   = (const float*)d_in[6];
    const float* be1  = (const float*)d_in[7];
    const float* w1_2 = (const float*)d_in[8];
    const float* b1_2 = (const float*)d_in[9];
    const float* w2_2 = (const float*)d_in[10];
    const float* b2_2 = (const float*)d_in[11];
    const float* g2   = (const float*)d_in[12];
    const float* be2  = (const float*)d_in[13];
    float* out = (float*)d_out;

    char* ws = (char*)d_ws;
    int*    offs    = (int*)(ws + OFF_OFFSETS);
    float*  scale1  = (float*)(ws + OFF_SCALE1);
    float*  shift1  = (float*)(ws + OFF_SHIFT1);
    float*  scale2  = (float*)(ws + OFF_SCALE2);
    float*  shift2  = (float*)(ws + OFF_SHIFT2);
    double* statp   = (double*)(ws + OFF_STATP);
    int*    rowcnt  = (int*)(ws + OFF_ROWCNT);    // overlays statp (disjoint lifetime)
    int*    rowbase = (int*)(ws + OFF_ROWBASE);
    float*  pooled1 = (float*)(ws + OFF_POOLED1);
    float*  pooled2 = (float*)(ws + OFF_POOLED2);
    float*  kbuf1   = (float*)(ws + OFF_KBUF1);
    float*  kbuf2   = (float*)(ws + OFF_KBUF2);
    int*    rmap    = (int*)(ws + OFF_RMAP);
    float*  rowsum  = (float*)(ws + OFF_RMAP);   // reuse: rmap dead after scatter
    int*    lists   = (int*)(ws + OFF_LISTS);
    float*  Xt      = (float*)(ws + OFF_XT);
    float*  rawY1   = (float*)(ws + OFF_RAWY1);

    hipLaunchKernelGGL(transpose16_kernel, dim3(HW/256, B_), dim3(256), 0, stream, x, Xt);
    hipLaunchKernelGGL(regionmap_kernel, dim3(H_, B_), dim3(256), 0, stream, hm, rmap, rowcnt);
    hipLaunchKernelGGL(scan2_kernel, dim3(1), dim3(256), 0, stream, rowcnt, offs, rowbase);
    hipLaunchKernelGGL(scatter_kernel, dim3(H_, B_), dim3(256), 0, stream, rmap, rowbase, lists);

    // ---- layer 1 ----
    hipLaunchKernelGGL((rowsum_kernel<CIN1,false>), dim3(H_, B_), dim3(256), 0, stream,
                       Xt, nullptr, nullptr, rowsum);
    hipLaunchKernelGGL((binreduce_kernel<CIN1>), dim3(9, B_), dim3(256), 0, stream,
                       rowsum, pooled1);
    hipLaunchKernelGGL((kgen_kernel<CIN1>), dim3(B_*R_), dim3(256), 0, stream,
                       pooled1, w1_1, b1_1, w2_1, b2_1, kbuf1);
    hipLaunchKernelGGL((conv_kernel<CIN1,false,true>), dim3(16, 32), dim3(256), 0, stream,
                       Xt, kbuf1, lists, offs, nullptr, nullptr, rawY1);
    hipLaunchKernelGGL(stats_nhwc_kernel, dim3(128), dim3(256), 0, stream, rawY1, statp);
    hipLaunchKernelGGL(bnfinal_kernel, dim3(1), dim3(32), 0, stream, statp, 128, g1, be1, scale1, shift1);

    // ---- layer 2 (BN1+ReLU fused into loads) ----
    hipLaunchKernelGGL((rowsum_kernel<CMID,true>), dim3(H_, B_), dim3(256), 0, stream,
                       rawY1, scale1, shift1, rowsum);
    hipLaunchKernelGGL((binreduce_kernel<CMID>), dim3(9, B_), dim3(256), 0, stream,
                       rowsum, pooled2);
    hipLaunchKernelGGL((kgen_kernel<CMID>), dim3(B_*R_), dim3(256), 0, stream,
                       pooled2, w1_2, b1_2, w2_2, b2_2, kbuf2);
    hipLaunchKernelGGL((conv_kernel<CMID,true,false>), dim3(16, 32), dim3(256), 0, stream,
                       rawY1, kbuf2, lists, offs, scale1, shift1, out);
    hipLaunchKernelGGL(stats_nchw_kernel, dim3(8, 32), dim3(256), 0, stream, out, statp);
    hipLaunchKernelGGL(bnfinal_kernel, dim3(1), dim3(32), 0, stream, statp, 8, g2, be2, scale2, shift2);
    hipLaunchKernelGGL(eltwise_kernel, dim3((B_*32*HW/4)/256), dim3(256), 0, stream, out, scale2, shift2);
}